// Round 3
// baseline (104.614 us; speedup 1.0000x reference)
//
#include <hip/hip_runtime.h>

// TwoStageRegressionLoss: fused BCE + duration-aware focal smooth-L1 mean
// reduction over N = 2048*16384 fp32 elements per array (4 input arrays).
// R1: libm logf made it VALU-bound (77%) -> hw __log2f (R2: 119.7->101.0us).
// R2 counters: VALUBusy 20%, HBM 22%, VGPR=16 -> latency-bound with ~1
// outstanding load/wave. R3: 2-deep software pipeline to keep 8 float4 loads
// in flight per wave (need ~4/wave at 23 waves/CU for ~6 TB/s).

constexpr int BLOCK = 256;
constexpr int GRID  = 2048;   // 256 CUs x 8 blocks; 16 float4 iters/thread at N=33.5M

__device__ __forceinline__ void accum_elem(float pv, float tv, float qv, float sv,
                                           float& accB, float& accR) {
    // --- BCE with torch-style log clamp at -100 ---
    constexpr float LN2 = 0.6931471805599453f;
    float pc = fminf(fmaxf(pv, 0.0f), 1.0f);
    float tc = fminf(fmaxf(tv, 0.0f), 1.0f);
    // hw transcendental: v_log_f32 computes log2; log(x) = log2(x)*ln2.
    // log2(0) = -inf -> clamped to -100 (matches torch/ref clamp).
    float lp  = fmaxf(__log2f(pc)        * LN2, -100.0f);
    float l1p = fmaxf(__log2f(1.0f - pc) * LN2, -100.0f);
    accB -= tc * lp + (1.0f - tc) * l1p;
    // --- duration-aware focal smooth-L1 (alpha=0.25, gamma=2, delta=0.5) ---
    float d = fabsf(qv - sv);
    float f = fminf(d + d, 1.0f);               // clip(d/0.5, 0, 1)
    float base = (d < 0.5f) ? (d * d) : (d - 0.25f);  // smooth L1, beta=0.5
    // class weight: round-half-even (matches jnp.round), clamp [0,3], table {1,4,3,2}
    float r = fminf(fmaxf(__builtin_rintf(sv), 0.0f), 3.0f);
    float w = (r == 0.0f) ? 1.0f : (r == 1.0f) ? 4.0f : (r == 2.0f) ? 3.0f : 2.0f;
    accR += 0.25f * (f * f) * base * w;
}

__device__ __forceinline__ void accum4(const float4& p, const float4& t,
                                       const float4& q, const float4& s,
                                       float& accB0, float& accR0,
                                       float& accB1, float& accR1) {
    accum_elem(p.x, t.x, q.x, s.x, accB0, accR0);
    accum_elem(p.y, t.y, q.y, s.y, accB1, accR1);
    accum_elem(p.z, t.z, q.z, s.z, accB0, accR0);
    accum_elem(p.w, t.w, q.w, s.w, accB1, accR1);
}

__global__ __launch_bounds__(BLOCK) void partial_kernel(
    const float4* __restrict__ bp4, const float4* __restrict__ rp4,
    const float4* __restrict__ bt4, const float4* __restrict__ rt4,
    float* __restrict__ partials, int n4, int n)
{
    float accB0 = 0.0f, accR0 = 0.0f, accB1 = 0.0f, accR1 = 0.0f;
    const int stride = gridDim.x * blockDim.x;
    int i = blockIdx.x * blockDim.x + threadIdx.x;
    if (i < n4) {
        // software pipeline: next iteration's 4 loads issue BEFORE current
        // iteration's math consumes its data -> 8 float4 loads in flight.
        float4 p = bp4[i], q = rp4[i], t = bt4[i], s = rt4[i];
        int j = i + stride;
        #pragma unroll 2
        while (j < n4) {
            float4 pn = bp4[j], qn = rp4[j], tn = bt4[j], sn = rt4[j];
            accum4(p, t, q, s, accB0, accR0, accB1, accR1);
            p = pn; q = qn; t = tn; s = sn;
            j += stride;
        }
        accum4(p, t, q, s, accB0, accR0, accB1, accR1);
    }
    // scalar tail (n not multiple of 4) -- handled by block 0 only
    if (blockIdx.x == 0) {
        const float* bp = (const float*)bp4;
        const float* bt = (const float*)bt4;
        const float* rp = (const float*)rp4;
        const float* rt = (const float*)rt4;
        for (int k = n4 * 4 + threadIdx.x; k < n; k += BLOCK)
            accum_elem(bp[k], bt[k], rp[k], rt[k], accB0, accR0);
    }
    float accB = accB0 + accB1;
    float accR = accR0 + accR1;
    // wave-64 reduce
    #pragma unroll
    for (int off = 32; off > 0; off >>= 1) {
        accB += __shfl_down(accB, off, 64);
        accR += __shfl_down(accR, off, 64);
    }
    __shared__ float sB[BLOCK / 64], sR[BLOCK / 64];
    const int lane = threadIdx.x & 63;
    const int wid  = threadIdx.x >> 6;
    if (lane == 0) { sB[wid] = accB; sR[wid] = accR; }
    __syncthreads();
    if (threadIdx.x == 0) {
        float b = 0.0f, r = 0.0f;
        #pragma unroll
        for (int w = 0; w < BLOCK / 64; ++w) { b += sB[w]; r += sR[w]; }
        partials[blockIdx.x]        = b;
        partials[GRID + blockIdx.x] = r;
    }
}

__global__ __launch_bounds__(BLOCK) void final_kernel(
    const float* __restrict__ partials, float* __restrict__ out, double invN)
{
    double accB = 0.0, accR = 0.0;
    for (int i = threadIdx.x; i < GRID; i += BLOCK) {
        accB += (double)partials[i];
        accR += (double)partials[GRID + i];
    }
    #pragma unroll
    for (int off = 32; off > 0; off >>= 1) {
        accB += __shfl_down(accB, off, 64);
        accR += __shfl_down(accR, off, 64);
    }
    __shared__ double dB[BLOCK / 64], dR[BLOCK / 64];
    const int lane = threadIdx.x & 63;
    const int wid  = threadIdx.x >> 6;
    if (lane == 0) { dB[wid] = accB; dR[wid] = accR; }
    __syncthreads();
    if (threadIdx.x == 0) {
        double b = 0.0, r = 0.0;
        #pragma unroll
        for (int w = 0; w < BLOCK / 64; ++w) { b += dB[w]; r += dR[w]; }
        const double bm = b * invN;
        const double rm = r * invN;
        out[0] = (float)(bm + rm);  // total = BREAK_W*break + REG_W*reg, both 1.0
        out[1] = (float)bm;         // break_loss
        out[2] = (float)rm;         // regression_loss
    }
}

extern "C" void kernel_launch(void* const* d_in, const int* in_sizes, int n_in,
                              void* d_out, int out_size, void* d_ws, size_t ws_size,
                              hipStream_t stream) {
    // setup_inputs() order: break_predictions, regression_predictions,
    //                       break_targets, regression_targets  (all fp32)
    const float* bp = (const float*)d_in[0];
    const float* rp = (const float*)d_in[1];
    const float* bt = (const float*)d_in[2];
    const float* rt = (const float*)d_in[3];
    const int n  = in_sizes[0];
    const int n4 = n / 4;
    float* partials = (float*)d_ws;   // 2*GRID floats = 16 KB scratch

    partial_kernel<<<GRID, BLOCK, 0, stream>>>(
        (const float4*)bp, (const float4*)rp, (const float4*)bt, (const float4*)rt,
        partials, n4, n);
    final_kernel<<<1, BLOCK, 0, stream>>>(partials, (float*)d_out, 1.0 / (double)n);
}